// Round 4
// baseline (1398.008 us; speedup 1.0000x reference)
//
#include <hip/hip_runtime.h>
#include <hip/hip_cooperative_groups.h>
#include <cstddef>

namespace cg = cooperative_groups;

// SlotAttention, single cooperative megakernel (256 blocks) + multi-kernel fallback.
//   xn = LN(x) stored bf16 once; k,v never materialized.
//   logits = (LN(slots) @ Wqk + bqk) @ xn^T,  Wqk = SCALE*Wq^T@Wk  (q.bk const cancels in softmax)
//   gi     = (attn@xn) @ Wihv^T + bihv,       Wihv = W_ih@Wv, bihv = W_ih@bv + b_ih
//   (+1e-8 renorm dropped: perturbation ~2e-5 << threshold)

#define BB 64
#define NN 2048
#define DD 256
#define NITER 3

typedef unsigned short u16;
typedef unsigned int u32;

__device__ __forceinline__ float bflo(u32 u){ return __uint_as_float(u<<16); }
__device__ __forceinline__ float bfhi(u32 u){ return __uint_as_float(u & 0xffff0000u); }
__device__ __forceinline__ u16 f2bf(float f){
  u32 u = __float_as_uint(f);
  u32 r = u + 0x7fffu + ((u>>16)&1u);
  return (u16)(r>>16);
}

struct Params {
  const float *x, *noise, *mu, *sig;
  const float *Wq, *bq, *Wk, *Wv, *bv, *Wih, *bih, *Whh, *bhh, *W1, *b1, *W2, *b2;
  const float *g_in, *be_in, *g_sl, *be_sl, *g_ff, *be_ff;
  float* out;
  u16* xn;
  float *Wqk, *bqk, *Wihv, *bihv;
  float *Scur, *Sg, *Ln, *Hh, *Uu, *Qq, *Gi, *Gh, *mP, *lP, *aP;
};

union SMem {
  struct { float qs[8][256]; float plT[256][8]; float4 red[4][8][64]; float mS[8]; float lS[8]; } a; // ~48.1 KB attn
  struct { float lnA[8][256]; } q;    // q-proj
  struct { float col[256]; } f;       // weight folds
  struct { float sh[8]; } s;          // row reductions
};

// C tile GEMM vs W[NC,256] (row-major, used as W^T), A[.,256]
template<int NC, int MODE>
__device__ __forceinline__ void gemm_tile(const float* __restrict__ A, const float* __restrict__ W,
                                          const float* __restrict__ bias, const float* __restrict__ R,
                                          float* __restrict__ C, int bx, int by){
  const int tx = threadIdx.x & 15, ty = threadIdx.x >> 4;
  const int r0 = bx*64 + ty*4, c0 = by*64 + tx*4;
  const float* a0 = A + (size_t)r0*256;
  const float* w0 = W + (size_t)c0*256;
  float acc[4][4] = {};
  #pragma unroll 2
  for(int k=0;k<256;k+=4){
    float4 av[4], wv[4];
    #pragma unroll
    for(int i=0;i<4;i++) av[i] = *(const float4*)(a0 + i*256 + k);
    #pragma unroll
    for(int j=0;j<4;j++) wv[j] = *(const float4*)(w0 + j*256 + k);
    #pragma unroll
    for(int i=0;i<4;i++)
      #pragma unroll
      for(int j=0;j<4;j++)
        acc[i][j] += av[i].x*wv[j].x + av[i].y*wv[j].y + av[i].z*wv[j].z + av[i].w*wv[j].w;
  }
  #pragma unroll
  for(int i=0;i<4;i++){
    #pragma unroll
    for(int j=0;j<4;j++){
      float v = acc[i][j] + bias[c0+j];
      if(MODE==1) v = fmaxf(v, 0.f);
      if(MODE==2) v += R[(size_t)(r0+i)*NC + c0 + j];
      C[(size_t)(r0+i)*NC + c0 + j] = v;
    }
  }
}

// ======================= cooperative megakernel (grid = 256) =======================
__global__ __launch_bounds__(256) void mega(Params p){
  cg::grid_group grid = cg::this_grid();
  __shared__ SMem sm;
  const int g = blockIdx.x, t = threadIdx.x, w = t>>6, l = t&63;

  // ---- stage 0: slots init + weight folds + LN(x)->bf16 ----
  {
    float sg = p.sig[t];
    float sp = fmaxf(sg, 0.f) + log1pf(expf(-fabsf(sg)));
    #pragma unroll
    for(int r=g; r<512; r+=256)
      p.Scur[r*256 + t] = p.mu[t] + sp * p.noise[r*256 + t];

    // Wqk row g
    sm.f.col[t] = p.Wq[t*256 + g];
    __syncthreads();
    {
      float acc = 0.f;
      #pragma unroll 4
      for(int j=0;j<256;j++) acc += sm.f.col[j]*p.Wk[j*256+t];
      p.Wqk[g*256+t] = acc * 0.0625f;
    }
    __syncthreads();
    // Wihv rows 3g..3g+2
    #pragma unroll
    for(int k=0;k<3;k++){
      int c = g*3 + k;
      sm.f.col[t] = p.Wih[c*256+t];
      __syncthreads();
      float acc = 0.f;
      #pragma unroll 4
      for(int j=0;j<256;j++) acc += sm.f.col[j]*p.Wv[j*256+t];
      p.Wihv[c*256+t] = acc;
      __syncthreads();
    }
    if(g == 0){                      // bqk
      float acc = 0.f;
      for(int j=0;j<256;j++) acc += p.bq[j]*p.Wk[j*256+t];
      p.bqk[t] = acc * 0.0625f;
    }
    if(g == 1){                      // bihv
      for(int c=t;c<768;c+=256){
        float acc = 0.f;
        for(int j=0;j<256;j++) acc += p.Wih[c*256+j]*p.bv[j];
        p.bihv[c] = acc + p.bih[c];
      }
    }

    // LN of x: 512 rows per block, 128 per wave
    const float4* gg4 = (const float4*)(p.g_in);
    const float4* bb4 = (const float4*)(p.be_in);
    float4 gg = gg4[l], bb = bb4[l];
    for(int i=0;i<128;++i){
      size_t row = (size_t)g*512 + (size_t)w*128 + i;
      float4 v = *(const float4*)(p.x + row*256 + l*4);
      float s1 = v.x+v.y+v.z+v.w;
      float s2 = v.x*v.x + v.y*v.y + v.z*v.z + v.w*v.w;
      #pragma unroll
      for(int off=1; off<64; off<<=1){ s1 += __shfl_xor(s1,off); s2 += __shfl_xor(s2,off); }
      float m = s1*(1.f/256.f);
      float var = s2*(1.f/256.f) - m*m;
      float rs = rsqrtf(var + 1e-5f);
      ushort4 o;
      o.x = f2bf((v.x-m)*rs*gg.x + bb.x);
      o.y = f2bf((v.y-m)*rs*gg.y + bb.y);
      o.z = f2bf((v.z-m)*rs*gg.z + bb.z);
      o.w = f2bf((v.w-m)*rs*gg.w + bb.w);
      *(ushort4*)(p.xn + row*256 + l*4) = o;
    }
  }
  grid.sync();

  for(int it=0; it<NITER; ++it){
    float* outp = (it==NITER-1) ? p.out : p.Scur;

    // ---- stage 1: q-proj (blocks 0-63) || gh-GEMM (blocks 64-159) ----
    if(g < 64){
      const int r0 = g*8;
      #pragma unroll
      for(int rr=0; rr<2; rr++){
        int r = w*2 + rr;
        float4 v = *(const float4*)(p.Scur + (size_t)(r0+r)*256 + l*4);
        float s1 = v.x+v.y+v.z+v.w;
        float s2 = v.x*v.x+v.y*v.y+v.z*v.z+v.w*v.w;
        #pragma unroll
        for(int off=1; off<64; off<<=1){ s1 += __shfl_xor(s1,off); s2 += __shfl_xor(s2,off); }
        float m = s1*(1.f/256.f);
        float var = s2*(1.f/256.f) - m*m;
        float rs = rsqrtf(var + 1e-5f);
        float4 gg = *(const float4*)(p.g_sl + l*4);
        float4 bb = *(const float4*)(p.be_sl + l*4);
        float4 o;
        o.x=(v.x-m)*rs*gg.x+bb.x; o.y=(v.y-m)*rs*gg.y+bb.y;
        o.z=(v.z-m)*rs*gg.z+bb.z; o.w=(v.w-m)*rs*gg.w+bb.w;
        *(float4*)(&sm.q.lnA[r][l*4]) = o;
      }
      __syncthreads();
      const int c4 = l*4;
      float acc[2][4] = {};
      #pragma unroll 2
      for(int k=0;k<256;k++){
        float4 wv = *(const float4*)(p.Wqk + (size_t)k*256 + c4);
        float a0 = sm.q.lnA[2*w][k], a1 = sm.q.lnA[2*w+1][k];
        acc[0][0]+=a0*wv.x; acc[0][1]+=a0*wv.y; acc[0][2]+=a0*wv.z; acc[0][3]+=a0*wv.w;
        acc[1][0]+=a1*wv.x; acc[1][1]+=a1*wv.y; acc[1][2]+=a1*wv.z; acc[1][3]+=a1*wv.w;
      }
      float4 bq4 = *(const float4*)(p.bqk + c4);
      #pragma unroll
      for(int rr=0; rr<2; rr++){
        float4 o;
        o.x=acc[rr][0]+bq4.x; o.y=acc[rr][1]+bq4.y; o.z=acc[rr][2]+bq4.z; o.w=acc[rr][3]+bq4.w;
        *(float4*)(p.Qq + (size_t)(r0+2*w+rr)*256 + c4) = o;
      }
      __syncthreads();
    } else if(g < 160){
      int tid = g - 64;
      gemm_tile<768,0>(p.Scur, p.Whh, p.bhh, nullptr, p.Gh, tid&7, tid>>3);
    }
    grid.sync();

    // ---- stage 2: attention partials (2 units per block) ----
    for(int u=g; u<512; u+=256){
      const int b = u>>3, c = u&7;
      for(int i=t;i<2048;i+=256) ((float*)sm.a.qs)[i] = p.Qq[b*2048 + i];
      __syncthreads();
      const uint4* xr = (const uint4*)(p.xn + ((size_t)(b*NN) + (size_t)c*256 + t)*DD);
      float lg[8]={0,0,0,0,0,0,0,0};
      #pragma unroll 2
      for(int d8=0; d8<32; ++d8){
        uint4 uu = xr[d8];
        float x0=bflo(uu.x), x1=bfhi(uu.x), x2=bflo(uu.y), x3=bfhi(uu.y);
        float x4=bflo(uu.z), x5=bfhi(uu.z), x6=bflo(uu.w), x7=bfhi(uu.w);
        #pragma unroll
        for(int s=0;s<8;s++){
          const float4* qrow = (const float4*)(&sm.a.qs[s][d8*8]);
          float4 qa = qrow[0], qb = qrow[1];
          lg[s] += qa.x*x0 + qa.y*x1 + qa.z*x2 + qa.w*x3
                 + qb.x*x4 + qb.y*x5 + qb.z*x6 + qb.w*x7;
        }
      }
      #pragma unroll
      for(int s=0;s<8;s++) sm.a.plT[t][s] = lg[s];
      __syncthreads();
      {
        int s = t>>5, l32 = t&31;
        float mx = -1e30f;
        #pragma unroll
        for(int k=0;k<8;k++) mx = fmaxf(mx, sm.a.plT[l32 + 32*k][s]);
        #pragma unroll
        for(int off=1; off<32; off<<=1) mx = fmaxf(mx, __shfl_xor(mx, off));
        if(l32==0) sm.a.mS[s] = mx;
      }
      __syncthreads();
      #pragma unroll
      for(int s=0;s<8;s++) sm.a.plT[t][s] = __expf(lg[s] - sm.a.mS[s]);
      __syncthreads();
      {
        int s = t>>5, l32 = t&31;
        float smm = 0.f;
        #pragma unroll
        for(int k=0;k<8;k++) smm += sm.a.plT[l32 + 32*k][s];
        #pragma unroll
        for(int off=1; off<32; off<<=1) smm += __shfl_xor(smm, off);
        if(l32==0) sm.a.lS[s] = smm;
      }
      float4 acc4[8] = {};
      const u16* base = p.xn + ((size_t)(b*NN) + (size_t)c*256)*DD;
      #pragma unroll 4
      for(int j=0;j<64;++j){
        int nl = w + 4*j;
        uint2 uu = *(const uint2*)(base + (size_t)nl*DD + l*4);
        float x0=bflo(uu.x), x1=bfhi(uu.x), x2=bflo(uu.y), x3=bfhi(uu.y);
        const float4* pr = (const float4*)(&sm.a.plT[nl][0]);
        float4 pa = pr[0], pb4 = pr[1];
        acc4[0].x += pa.x*x0; acc4[0].y += pa.x*x1; acc4[0].z += pa.x*x2; acc4[0].w += pa.x*x3;
        acc4[1].x += pa.y*x0; acc4[1].y += pa.y*x1; acc4[1].z += pa.y*x2; acc4[1].w += pa.y*x3;
        acc4[2].x += pa.z*x0; acc4[2].y += pa.z*x1; acc4[2].z += pa.z*x2; acc4[2].w += pa.z*x3;
        acc4[3].x += pa.w*x0; acc4[3].y += pa.w*x1; acc4[3].z += pa.w*x2; acc4[3].w += pa.w*x3;
        acc4[4].x += pb4.x*x0; acc4[4].y += pb4.x*x1; acc4[4].z += pb4.x*x2; acc4[4].w += pb4.x*x3;
        acc4[5].x += pb4.y*x0; acc4[5].y += pb4.y*x1; acc4[5].z += pb4.y*x2; acc4[5].w += pb4.y*x3;
        acc4[6].x += pb4.z*x0; acc4[6].y += pb4.z*x1; acc4[6].z += pb4.z*x2; acc4[6].w += pb4.z*x3;
        acc4[7].x += pb4.w*x0; acc4[7].y += pb4.w*x1; acc4[7].z += pb4.w*x2; acc4[7].w += pb4.w*x3;
      }
      #pragma unroll
      for(int s=0;s<8;s++) sm.a.red[w][s][l] = acc4[s];
      __syncthreads();
      size_t pb = (size_t)(b*8 + c)*8;
      for(int idx=t; idx<512; idx+=256){
        int s = idx>>6, ll = idx&63;
        float4 r0=sm.a.red[0][s][ll], r1=sm.a.red[1][s][ll], r2=sm.a.red[2][s][ll], r3=sm.a.red[3][s][ll];
        float4 o;
        o.x=r0.x+r1.x+r2.x+r3.x; o.y=r0.y+r1.y+r2.y+r3.y;
        o.z=r0.z+r1.z+r2.z+r3.z; o.w=r0.w+r1.w+r2.w+r3.w;
        *(float4*)(p.aP + pb*256 + s*256 + ll*4) = o;
      }
      if(t<8){ p.mP[pb+t] = sm.a.mS[t]; p.lP[pb+t] = sm.a.lS[t]; }
      __syncthreads();
    }
    grid.sync();

    // ---- stage 3: combine partials -> U (2 rows per block) ----
    for(int r=g; r<512; r+=256){
      int b = r>>3, s = r&7;
      float M = -1e30f;
      #pragma unroll
      for(int c=0;c<8;c++) M = fmaxf(M, p.mP[(b*8+c)*8 + s]);
      float wc[8]; float L = 0.f;
      #pragma unroll
      for(int c=0;c<8;c++){ wc[c] = __expf(p.mP[(b*8+c)*8+s] - M); L += p.lP[(b*8+c)*8+s]*wc[c]; }
      float u = 0.f;
      #pragma unroll
      for(int c=0;c<8;c++) u += wc[c]*p.aP[(size_t)((b*8+c)*8+s)*256 + t];
      p.Uu[r*256+t] = u / L;
    }
    grid.sync();

    // ---- stage 4: gi-GEMM ----
    if(g < 96) gemm_tile<768,0>(p.Uu, p.Wihv, p.bihv, nullptr, p.Gi, g&7, g>>3);
    grid.sync();

    // ---- stage 5: GRU gates + LN_ff (2 rows per block) ----
    for(int r=g; r<512; r+=256){
      const float* gi = p.Gi + (size_t)r*768;
      const float* gh = p.Gh + (size_t)r*768;
      float ir=gi[t], iz=gi[256+t], inn=gi[512+t];
      float hr=gh[t], hz=gh[256+t], hn=gh[512+t];
      float rr2 = 1.f/(1.f + __expf(-(ir+hr)));
      float zz = 1.f/(1.f + __expf(-(iz+hz)));
      float nn = tanhf(inn + rr2*hn);
      float prev = p.Scur[r*256+t];
      float sp = (1.f-zz)*nn + zz*prev;
      p.Sg[r*256+t] = sp;
      float s1=sp, s2=sp*sp;
      #pragma unroll
      for(int off=1; off<64; off<<=1){ s1 += __shfl_xor(s1,off); s2 += __shfl_xor(s2,off); }
      if(l==0){ sm.s.sh[w]=s1; sm.s.sh[4+w]=s2; }
      __syncthreads();
      float t1=sm.s.sh[0]+sm.s.sh[1]+sm.s.sh[2]+sm.s.sh[3];
      float t2=sm.s.sh[4]+sm.s.sh[5]+sm.s.sh[6]+sm.s.sh[7];
      float m = t1*(1.f/256.f);
      float var = t2*(1.f/256.f) - m*m;
      float rs = rsqrtf(var + 1e-5f);
      p.Ln[r*256+t] = (sp-m)*rs*p.g_ff[t] + p.be_ff[t];
      __syncthreads();
    }
    grid.sync();

    // ---- stage 6: W1 + relu ----
    if(g < 32) gemm_tile<256,1>(p.Ln, p.W1, p.b1, nullptr, p.Hh, g&7, g>>3);
    grid.sync();

    // ---- stage 7: W2 + residual ----
    if(g < 32) gemm_tile<256,2>(p.Hh, p.W2, p.b2, p.Sg, outp, g&7, g>>3);
    grid.sync();
  }
}

// ======================= fallback multi-kernel path (verified R2) =======================
__device__ __forceinline__ float2 block_meanrstd(float v, float* sh){
  float s1=v, s2=v*v;
  #pragma unroll
  for(int off=1; off<64; off<<=1){ s1 += __shfl_xor(s1,off); s2 += __shfl_xor(s2,off); }
  int w = threadIdx.x>>6;
  if((threadIdx.x&63)==0){ sh[w]=s1; sh[4+w]=s2; }
  __syncthreads();
  float t1=sh[0]+sh[1]+sh[2]+sh[3];
  float t2=sh[4]+sh[5]+sh[6]+sh[7];
  float m = t1*(1.f/256.f);
  float var = t2*(1.f/256.f) - m*m;
  return make_float2(m, rsqrtf(var + 1e-5f));
}

__global__ __launch_bounds__(256) void k_init(const float* __restrict__ noise, const float* __restrict__ mu,
                                              const float* __restrict__ sig, float* __restrict__ S,
                                              const float* __restrict__ Wq, const float* __restrict__ Wk,
                                              const float* __restrict__ bq, const float* __restrict__ Wih,
                                              const float* __restrict__ Wv, const float* __restrict__ bv,
                                              const float* __restrict__ bih,
                                              float* __restrict__ Wqk, float* __restrict__ bqk,
                                              float* __restrict__ Wihv, float* __restrict__ bihv){
  __shared__ float col[256];
  int blk = blockIdx.x, t = threadIdx.x;
  if(blk < 512){
    int i = blk*256 + t;
    int d = i & 255;
    float sg = sig[d];
    float sp = fmaxf(sg, 0.f) + log1pf(expf(-fabsf(sg)));
    S[i] = mu[d] + sp * noise[i];
  } else if(blk < 768){
    int d1 = blk - 512;
    col[t] = Wq[t*256 + d1];
    __syncthreads();
    float acc = 0.f;
    #pragma unroll 4
    for(int j=0;j<256;j++) acc += col[j]*Wk[j*256+t];
    Wqk[d1*256+t] = acc * 0.0625f;
  } else if(blk < 1536){
    int c = blk - 768;
    col[t] = Wih[c*256+t];
    __syncthreads();
    float acc = 0.f;
    #pragma unroll 4
    for(int j=0;j<256;j++) acc += col[j]*Wv[j*256+t];
    Wihv[c*256+t] = acc;
  } else if(blk == 1536){
    float acc = 0.f;
    for(int j=0;j<256;j++) acc += bq[j]*Wk[j*256+t];
    bqk[t] = acc * 0.0625f;
  } else {
    for(int c=t;c<768;c+=256){
      float acc = 0.f;
      for(int j=0;j<256;j++) acc += Wih[c*256+j]*bv[j];
      bihv[c] = acc + bih[c];
    }
  }
}

__global__ __launch_bounds__(256) void k_ln(const float* __restrict__ x, const float* __restrict__ g,
                                            const float* __restrict__ be, u16* __restrict__ xn){
  int wave = threadIdx.x>>6, lane = threadIdx.x&63;
  size_t row = (size_t)blockIdx.x*4 + wave;
  const float* xr = x + row*256;
  float4 v = *(const float4*)(xr + lane*4);
  float s1 = v.x+v.y+v.z+v.w;
  float s2 = v.x*v.x + v.y*v.y + v.z*v.z + v.w*v.w;
  #pragma unroll
  for(int off=1; off<64; off<<=1){ s1 += __shfl_xor(s1,off); s2 += __shfl_xor(s2,off); }
  float m = s1*(1.f/256.f);
  float var = s2*(1.f/256.f) - m*m;
  float rs = rsqrtf(var + 1e-5f);
  float4 gg = *(const float4*)(g + lane*4);
  float4 bb = *(const float4*)(be + lane*4);
  ushort4 o;
  o.x = f2bf((v.x-m)*rs*gg.x + bb.x);
  o.y = f2bf((v.y-m)*rs*gg.y + bb.y);
  o.z = f2bf((v.z-m)*rs*gg.z + bb.z);
  o.w = f2bf((v.w-m)*rs*gg.w + bb.w);
  *(ushort4*)(xn + row*256 + lane*4) = o;
}

__global__ __launch_bounds__(256) void k_q(const float* __restrict__ Sc, const float* __restrict__ g,
                                           const float* __restrict__ be, const float* __restrict__ Wqk,
                                           const float* __restrict__ bqk, float* __restrict__ Q){
  __shared__ float lnA[8][256];
  const int t = threadIdx.x, w = t>>6, l = t&63;
  const int r0 = blockIdx.x*8;
  #pragma unroll
  for(int rr=0; rr<2; rr++){
    int r = w*2 + rr;
    float4 v = *(const float4*)(Sc + (size_t)(r0+r)*256 + l*4);
    float s1 = v.x+v.y+v.z+v.w;
    float s2 = v.x*v.x+v.y*v.y+v.z*v.z+v.w*v.w;
    #pragma unroll
    for(int off=1; off<64; off<<=1){ s1 += __shfl_xor(s1,off); s2 += __shfl_xor(s2,off); }
    float m = s1*(1.f/256.f);
    float var = s2*(1.f/256.f) - m*m;
    float rs = rsqrtf(var + 1e-5f);
    float4 gg = *(const float4*)(g + l*4);
    float4 bb = *(const float4*)(be + l*4);
    float4 o;
    o.x=(v.x-m)*rs*gg.x+bb.x; o.y=(v.y-m)*rs*gg.y+bb.y;
    o.z=(v.z-m)*rs*gg.z+bb.z; o.w=(v.w-m)*rs*gg.w+bb.w;
    *(float4*)(&lnA[r][l*4]) = o;
  }
  __syncthreads();
  const int c4 = l*4;
  float acc[2][4] = {};
  #pragma unroll 2
  for(int k=0;k<256;k++){
    float4 wv = *(const float4*)(Wqk + (size_t)k*256 + c4);
    float a0 = lnA[2*w][k], a1 = lnA[2*w+1][k];
    acc[0][0]+=a0*wv.x; acc[0][1]+=a0*wv.y; acc[0][2]+=a0*wv.z; acc[0][3]+=a0*wv.w;
    acc[1][0]+=a1*wv.x; acc[1][1]+=a1*wv.y; acc[1][2]+=a1*wv.z; acc[1][3]+=a1*wv.w;
  }
  float4 bq4 = *(const float4*)(bqk + c4);
  #pragma unroll
  for(int rr=0; rr<2; rr++){
    float4 o;
    o.x=acc[rr][0]+bq4.x; o.y=acc[rr][1]+bq4.y; o.z=acc[rr][2]+bq4.z; o.w=acc[rr][3]+bq4.w;
    *(float4*)(Q + (size_t)(r0+2*w+rr)*256 + c4) = o;
  }
}

__global__ __launch_bounds__(256) void k_attn(const u16* __restrict__ xn, const float* __restrict__ Q,
                                              float* __restrict__ mP, float* __restrict__ lP,
                                              float* __restrict__ aP){
  __shared__ float qs[8][256];
  __shared__ float plT[256][8];
  __shared__ float mS[8], lS[8];
  __shared__ float4 red[4][8][64];
  const int b = blockIdx.x, c = blockIdx.y, t = threadIdx.x;
  const int w = t>>6, l = t&63;
  for(int i=t;i<2048;i+=256) ((float*)qs)[i] = Q[b*2048 + i];
  __syncthreads();
  const uint4* xr = (const uint4*)(xn + ((size_t)(b*NN) + (size_t)c*256 + t)*DD);
  float lg[8]={0,0,0,0,0,0,0,0};
  #pragma unroll 2
  for(int d8=0; d8<32; ++d8){
    uint4 u = xr[d8];
    float x0=bflo(u.x), x1=bfhi(u.x), x2=bflo(u.y), x3=bfhi(u.y);
    float x4=bflo(u.z), x5=bfhi(u.z), x6=bflo(u.w), x7=bfhi(u.w);
    #pragma unroll
    for(int s=0;s<8;s++){
      const float4* qrow = (const float4*)(&qs[s][d8*8]);
      float4 qa = qrow[0], qb = qrow[1];
      lg[s] += qa.x*x0 + qa.y*x1 + qa.z*x2 + qa.w*x3
             + qb.x*x4 + qb.y*x5 + qb.z*x6 + qb.w*x7;
    }
  }
  #pragma unroll
  for(int s=0;s<8;s++) plT[t][s] = lg[s];
  __syncthreads();
  {
    int s = t>>5, l32 = t&31;
    float mx = -1e30f;
    #pragma unroll
    for(int k=0;k<8;k++) mx = fmaxf(mx, plT[l32 + 32*k][s]);
    #pragma unroll
    for(int off=1; off<32; off<<=1) mx = fmaxf(mx, __shfl_xor(mx, off));
    if(l32==0) mS[s] = mx;
  }
  __syncthreads();
  #pragma unroll
  for(int s=0;s<8;s++) plT[t][s] = __expf(lg[s] - mS[s]);
  __syncthreads();
  {
    int s = t>>5, l32 = t&31;
    float sm = 0.f;
    #pragma unroll
    for(int k=0;k<8;k++) sm += plT[l32 + 32*k][s];
    #pragma unroll
    for(int off=1; off<32; off<<=1) sm += __shfl_xor(sm, off);
    if(l32==0) lS[s] = sm;
  }
  float4 acc4[8] = {};
  const u16* base = xn + ((size_t)(b*NN) + (size_t)c*256)*DD;
  #pragma unroll 4
  for(int j=0;j<64;++j){
    int nl = w + 4*j;
    uint2 u = *(const uint2*)(base + (size_t)nl*DD + l*4);
    float x0=bflo(u.x), x1=bfhi(u.x), x2=bflo(u.y), x3=bfhi(u.y);
    const float4* pr = (const float4*)(&plT[nl][0]);
    float4 pa = pr[0], pb4 = pr[1];
    acc4[0].x += pa.x*x0; acc4[0].y += pa.x*x1; acc4[0].z += pa.x*x2; acc4[0].w += pa.x*x3;
    acc4[1].x += pa.y*x0; acc4[1].y += pa.y*x1; acc4[1].z += pa.y*x2; acc4[1].w += pa.y*x3;
    acc4[2].x += pa.z*x0; acc4[2].y += pa.z*x1; acc4[2].z += pa.z*x2; acc4[2].w += pa.z*x3;
    acc4[3].x += pa.w*x0; acc4[3].y += pa.w*x1; acc4[3].z += pa.w*x2; acc4[3].w += pa.w*x3;
    acc4[4].x += pb4.x*x0; acc4[4].y += pb4.x*x1; acc4[4].z += pb4.x*x2; acc4[4].w += pb4.x*x3;
    acc4[5].x += pb4.y*x0; acc4[5].y += pb4.y*x1; acc4[5].z += pb4.y*x2; acc4[5].w += pb4.y*x3;
    acc4[6].x += pb4.z*x0; acc4[6].y += pb4.z*x1; acc4[6].z += pb4.z*x2; acc4[6].w += pb4.z*x3;
    acc4[7].x += pb4.w*x0; acc4[7].y += pb4.w*x1; acc4[7].z += pb4.w*x2; acc4[7].w += pb4.w*x3;
  }
  #pragma unroll
  for(int s=0;s<8;s++) red[w][s][l] = acc4[s];
  __syncthreads();
  size_t pb = (size_t)(b*8 + c)*8;
  for(int idx=t; idx<512; idx+=256){
    int s = idx>>6, ll = idx&63;
    float4 r0=red[0][s][ll], r1=red[1][s][ll], r2=red[2][s][ll], r3=red[3][s][ll];
    float4 o;
    o.x=r0.x+r1.x+r2.x+r3.x; o.y=r0.y+r1.y+r2.y+r3.y;
    o.z=r0.z+r1.z+r2.z+r3.z; o.w=r0.w+r1.w+r2.w+r3.w;
    *(float4*)(aP + pb*256 + s*256 + ll*4) = o;
  }
  if(t<8){ mP[pb+t] = mS[t]; lP[pb+t] = lS[t]; }
}

__global__ __launch_bounds__(256) void k_comb(const float* __restrict__ mP, const float* __restrict__ lP,
                                              const float* __restrict__ aP, float* __restrict__ U){
  int r = blockIdx.x;
  int b = r>>3, s = r&7, t = threadIdx.x;
  float M = -1e30f;
  #pragma unroll
  for(int c=0;c<8;c++) M = fmaxf(M, mP[(b*8+c)*8 + s]);
  float w[8]; float L = 0.f;
  #pragma unroll
  for(int c=0;c<8;c++){ w[c] = __expf(mP[(b*8+c)*8+s] - M); L += lP[(b*8+c)*8+s]*w[c]; }
  float u = 0.f;
  #pragma unroll
  for(int c=0;c<8;c++) u += w[c]*aP[(size_t)((b*8+c)*8+s)*256 + t];
  U[r*256+t] = u / L;
}

__global__ __launch_bounds__(256) void k_gigh(const float* __restrict__ U, const float* __restrict__ Wihv,
                                              const float* __restrict__ bihv, const float* __restrict__ Sc,
                                              const float* __restrict__ Whh, const float* __restrict__ bhh,
                                              float* __restrict__ Gi, float* __restrict__ Gh){
  if(blockIdx.z==0) gemm_tile<768,0>(U,  Wihv, bihv, nullptr, Gi, blockIdx.x, blockIdx.y);
  else              gemm_tile<768,0>(Sc, Whh,  bhh,  nullptr, Gh, blockIdx.x, blockIdx.y);
}
__global__ __launch_bounds__(256) void k_w1(const float* __restrict__ Ln, const float* __restrict__ W1m,
                                            const float* __restrict__ b1v, float* __restrict__ H){
  gemm_tile<256,1>(Ln, W1m, b1v, nullptr, H, blockIdx.x, blockIdx.y);
}
__global__ __launch_bounds__(256) void k_w2(const float* __restrict__ H, const float* __restrict__ W2m,
                                            const float* __restrict__ b2v, const float* __restrict__ Sg,
                                            float* __restrict__ C){
  gemm_tile<256,2>(H, W2m, b2v, Sg, C, blockIdx.x, blockIdx.y);
}

__global__ __launch_bounds__(256) void k_gates(const float* __restrict__ Gi, const float* __restrict__ Gh,
                                               const float* __restrict__ Sc, const float* __restrict__ g,
                                               const float* __restrict__ be, float* __restrict__ Sg,
                                               float* __restrict__ Ln){
  __shared__ float sh[8];
  int r = blockIdx.x, t = threadIdx.x;
  const float* gi = Gi + (size_t)r*768;
  const float* gh = Gh + (size_t)r*768;
  float ir=gi[t], iz=gi[256+t], inn=gi[512+t];
  float hr=gh[t], hz=gh[256+t], hn=gh[512+t];
  float rr = 1.f/(1.f + __expf(-(ir+hr)));
  float zz = 1.f/(1.f + __expf(-(iz+hz)));
  float nn = tanhf(inn + rr*hn);
  float prev = Sc[r*256+t];
  float sp = (1.f-zz)*nn + zz*prev;
  Sg[r*256+t] = sp;
  float2 mr = block_meanrstd(sp, sh);
  Ln[r*256+t] = (sp-mr.x)*mr.y*g[t] + be[t];
}

extern "C" void kernel_launch(void* const* d_in, const int* in_sizes, int n_in,
                              void* d_out, int out_size, void* d_ws, size_t ws_size,
                              hipStream_t stream){
  Params p;
  p.x    = (const float*)d_in[0];
  p.noise= (const float*)d_in[1];
  p.mu   = (const float*)d_in[2];
  p.sig  = (const float*)d_in[3];
  p.Wq   = (const float*)d_in[4];
  p.bq   = (const float*)d_in[5];
  p.Wk   = (const float*)d_in[6];
  // d_in[7] = bk : constant shift over n, cancels in softmax
  p.Wv   = (const float*)d_in[8];
  p.bv   = (const float*)d_in[9];
  p.Wih  = (const float*)d_in[10];
  p.bih  = (const float*)d_in[11];
  p.Whh  = (const float*)d_in[12];
  p.bhh  = (const float*)d_in[13];
  p.W1   = (const float*)d_in[14];
  p.b1   = (const float*)d_in[15];
  p.W2   = (const float*)d_in[16];
  p.b2   = (const float*)d_in[17];
  p.g_in = (const float*)d_in[18];
  p.be_in= (const float*)d_in[19];
  p.g_sl = (const float*)d_in[20];
  p.be_sl= (const float*)d_in[21];
  p.g_ff = (const float*)d_in[22];
  p.be_ff= (const float*)d_in[23];
  p.out  = (float*)d_out;

  char* q = (char*)d_ws;
  auto alloc = [&](size_t bytes)->char*{ char* r = q; q += (bytes + 255) & ~(size_t)255; return r; };
  p.xn   = (u16*)  alloc((size_t)BB*NN*DD*2);
  p.Wqk  = (float*)alloc(256*256*4);
  p.bqk  = (float*)alloc(256*4);
  p.Wihv = (float*)alloc(768*256*4);
  p.bihv = (float*)alloc(768*4);
  p.Scur = (float*)alloc(512*256*4);
  p.Sg   = (float*)alloc(512*256*4);
  p.Ln   = (float*)alloc(512*256*4);
  p.Hh   = (float*)alloc(512*256*4);
  p.Uu   = (float*)alloc(512*256*4);
  p.Qq   = (float*)alloc(512*256*4);
  p.Gi   = (float*)alloc((size_t)512*768*4);
  p.Gh   = (float*)alloc((size_t)512*768*4);
  p.mP   = (float*)alloc(64*8*8*4);
  p.lP   = (float*)alloc(64*8*8*4);
  p.aP   = (float*)alloc((size_t)64*8*8*256*4);
  if((size_t)(q - (char*)d_ws) > ws_size) return;

  void* args[] = { (void*)&p };
  hipError_t err = hipLaunchCooperativeKernel((const void*)mega, dim3(256), dim3(256), args, 0, stream);
  if(err != hipSuccess){
    // fallback: verified multi-kernel path (R2)
    k_init<<<1538, 256, 0, stream>>>(p.noise, p.mu, p.sig, p.Scur, p.Wq, p.Wk, p.bq, p.Wih, p.Wv, p.bv, p.bih,
                                     p.Wqk, p.bqk, p.Wihv, p.bihv);
    k_ln<<<32768, 256, 0, stream>>>(p.x, p.g_in, p.be_in, p.xn);
    for(int it=0; it<NITER; ++it){
      k_q<<<64, 256, 0, stream>>>(p.Scur, p.g_sl, p.be_sl, p.Wqk, p.bqk, p.Qq);
      k_attn<<<dim3(64, 8), 256, 0, stream>>>(p.xn, p.Qq, p.mP, p.lP, p.aP);
      k_comb<<<512, 256, 0, stream>>>(p.mP, p.lP, p.aP, p.Uu);
      k_gigh<<<dim3(8,12,2), 256, 0, stream>>>(p.Uu, p.Wihv, p.bihv, p.Scur, p.Whh, p.bhh, p.Gi, p.Gh);
      k_gates<<<512, 256, 0, stream>>>(p.Gi, p.Gh, p.Scur, p.g_ff, p.be_ff, p.Sg, p.Ln);
      k_w1<<<dim3(8,4), 256, 0, stream>>>(p.Ln, p.W1, p.b1, p.Hh);
      float* outp = (it==NITER-1) ? p.out : p.Scur;
      k_w2<<<dim3(8,4), 256, 0, stream>>>(p.Hh, p.W2, p.b2, p.Sg, outp);
    }
  }
}

// Round 5
// 486.465 us; speedup vs baseline: 2.8738x; 2.8738x over previous
//
#include <hip/hip_runtime.h>
#include <cstddef>

// SlotAttention, multi-kernel, occupancy-tuned.
//   xn = LN(x) stored bf16 once; k,v never materialized.
//   logits = (LN(slots) @ Wqk + bqk) @ xn^T,  Wqk = SCALE*Wq^T@Wk  (q.bk const cancels in softmax)
//   gi     = (attn@xn) @ Wihv^T + bihv,       Wihv = W_ih@Wv, bihv = W_ih@bv + b_ih
//   (+1e-8 renorm dropped: perturbation ~2e-5 << threshold)

#define BB 64
#define NN 2048
#define DD 256
#define NCH 4      // n-chunks per batch (512 rows each)
#define CHK 512
#define NITER 3

typedef unsigned short u16;
typedef unsigned int u32;

__device__ __forceinline__ float bflo(u32 u){ return __uint_as_float(u<<16); }
__device__ __forceinline__ float bfhi(u32 u){ return __uint_as_float(u & 0xffff0000u); }
__device__ __forceinline__ u16 f2bf(float f){
  u32 u = __float_as_uint(f);
  u32 r = u + 0x7fffu + ((u>>16)&1u);
  return (u16)(r>>16);
}

// ---- init: slots prep + weight folds ----
__global__ __launch_bounds__(256) void k_init(const float* __restrict__ noise, const float* __restrict__ mu,
                                              const float* __restrict__ sig, float* __restrict__ S,
                                              const float* __restrict__ Wq, const float* __restrict__ Wk,
                                              const float* __restrict__ bq, const float* __restrict__ Wih,
                                              const float* __restrict__ Wv, const float* __restrict__ bv,
                                              const float* __restrict__ bih,
                                              float* __restrict__ Wqk, float* __restrict__ bqk,
                                              float* __restrict__ Wihv, float* __restrict__ bihv){
  __shared__ float col[256];
  int blk = blockIdx.x, t = threadIdx.x;
  if(blk < 512){
    int i = blk*256 + t;
    int d = i & 255;
    float sg = sig[d];
    float sp = fmaxf(sg, 0.f) + log1pf(expf(-fabsf(sg)));
    S[i] = mu[d] + sp * noise[i];
  } else if(blk < 768){
    int d1 = blk - 512;
    col[t] = Wq[t*256 + d1];
    __syncthreads();
    float acc = 0.f;
    #pragma unroll 4
    for(int j=0;j<256;j++) acc += col[j]*Wk[j*256+t];
    Wqk[d1*256+t] = acc * 0.0625f;
  } else if(blk < 1536){
    int c = blk - 768;
    col[t] = Wih[c*256+t];
    __syncthreads();
    float acc = 0.f;
    #pragma unroll 4
    for(int j=0;j<256;j++) acc += col[j]*Wv[j*256+t];
    Wihv[c*256+t] = acc;
  } else if(blk == 1536){
    float acc = 0.f;
    for(int j=0;j<256;j++) acc += bq[j]*Wk[j*256+t];
    bqk[t] = acc * 0.0625f;
  } else {
    for(int c=t;c<768;c+=256){
      float acc = 0.f;
      for(int j=0;j<256;j++) acc += Wih[c*256+j]*bv[j];
      bihv[c] = acc + bih[c];
    }
  }
}

// ---- xn = LN(x)*g+b -> bf16 ; one wave per row ----
__global__ __launch_bounds__(256) void k_ln(const float* __restrict__ x, const float* __restrict__ g,
                                            const float* __restrict__ be, u16* __restrict__ xn){
  int wave = threadIdx.x>>6, lane = threadIdx.x&63;
  size_t row = (size_t)blockIdx.x*4 + wave;
  const float* xr = x + row*256;
  float4 v = *(const float4*)(xr + lane*4);
  float s1 = v.x+v.y+v.z+v.w;
  float s2 = v.x*v.x + v.y*v.y + v.z*v.z + v.w*v.w;
  #pragma unroll
  for(int off=1; off<64; off<<=1){ s1 += __shfl_xor(s1,off); s2 += __shfl_xor(s2,off); }
  float m = s1*(1.f/256.f);
  float var = s2*(1.f/256.f) - m*m;
  float rs = rsqrtf(var + 1e-5f);
  float4 gg = *(const float4*)(g + lane*4);
  float4 bb = *(const float4*)(be + lane*4);
  ushort4 o;
  o.x = f2bf((v.x-m)*rs*gg.x + bb.x);
  o.y = f2bf((v.y-m)*rs*gg.y + bb.y);
  o.z = f2bf((v.z-m)*rs*gg.z + bb.z);
  o.w = f2bf((v.w-m)*rs*gg.w + bb.w);
  *(ushort4*)(xn + row*256 + lane*4) = o;
}

// ---- q~ = LN_sl(slots) @ Wqk + bqk ; grid (64 b, 4 col-strips), 512 thr ----
__global__ __launch_bounds__(512) void k_q(const float* __restrict__ Sc, const float* __restrict__ g,
                                           const float* __restrict__ be, const float* __restrict__ Wqk,
                                           const float* __restrict__ bqk, float* __restrict__ Q){
  __shared__ float lnA[8][256];
  const int t = threadIdx.x, r = t>>6, l = t&63;
  const int b = blockIdx.x, cb = blockIdx.y;
  // LN: wave r handles slot-row r of batch b
  {
    float4 v = *(const float4*)(Sc + (size_t)(b*8+r)*256 + l*4);
    float s1 = v.x+v.y+v.z+v.w;
    float s2 = v.x*v.x+v.y*v.y+v.z*v.z+v.w*v.w;
    #pragma unroll
    for(int off=1; off<64; off<<=1){ s1 += __shfl_xor(s1,off); s2 += __shfl_xor(s2,off); }
    float m = s1*(1.f/256.f);
    float var = s2*(1.f/256.f) - m*m;
    float rs = rsqrtf(var + 1e-5f);
    float4 gg = *(const float4*)(g + l*4);
    float4 bb = *(const float4*)(be + l*4);
    float4 o;
    o.x=(v.x-m)*rs*gg.x+bb.x; o.y=(v.y-m)*rs*gg.y+bb.y;
    o.z=(v.z-m)*rs*gg.z+bb.z; o.w=(v.w-m)*rs*gg.w+bb.w;
    *(float4*)(&lnA[r][l*4]) = o;
  }
  __syncthreads();
  // GEMM: thread (r, c): full 256-dot
  const int c = cb*64 + l;
  float acc = bqk[c];
  #pragma unroll 4
  for(int d=0; d<256; d++) acc += lnA[r][d]*Wqk[(size_t)d*256 + c];
  Q[(size_t)(b*8+r)*256 + c] = acc;
}

// ---- attention partials: grid (64 b, 4 chunks), 512 thr, chunk = 512 n-rows ----
__global__ __launch_bounds__(512) void k_attn(const u16* __restrict__ xn, const float* __restrict__ Q,
                                              float* __restrict__ mP, float* __restrict__ lP,
                                              float* __restrict__ aP){
  __shared__ float qs[8][256];      // 8 KB
  __shared__ float plT[512][8];     // 16 KB
  __shared__ float4 red[4][8][64];  // 32 KB
  __shared__ float mS[8], lS[8];
  const int b = blockIdx.x, c = blockIdx.y, t = threadIdx.x;
  const int w = t>>6, l = t&63;
  for(int i=t;i<2048;i+=512) ((float*)qs)[i] = Q[b*2048 + i];
  __syncthreads();
  // logits: thread t owns n-row t of the 512-row chunk
  const uint4* xr = (const uint4*)(xn + ((size_t)(b*NN) + (size_t)c*CHK + t)*DD);
  float lg[8]={0,0,0,0,0,0,0,0};
  #pragma unroll 2
  for(int d8=0; d8<32; ++d8){
    uint4 u = xr[d8];
    float x0=bflo(u.x), x1=bfhi(u.x), x2=bflo(u.y), x3=bfhi(u.y);
    float x4=bflo(u.z), x5=bfhi(u.z), x6=bflo(u.w), x7=bfhi(u.w);
    #pragma unroll
    for(int s=0;s<8;s++){
      const float4* qrow = (const float4*)(&qs[s][d8*8]);
      float4 qa = qrow[0], qb = qrow[1];
      lg[s] += qa.x*x0 + qa.y*x1 + qa.z*x2 + qa.w*x3
             + qb.x*x4 + qb.y*x5 + qb.z*x6 + qb.w*x7;
    }
  }
  #pragma unroll
  for(int s=0;s<8;s++) plT[t][s] = lg[s];
  __syncthreads();
  {  // per-s chunk max: s-group = wave (64 lanes)
    int s = t>>6, l64 = t&63;
    float mx = -1e30f;
    #pragma unroll
    for(int k=0;k<8;k++) mx = fmaxf(mx, plT[l64 + 64*k][s]);
    #pragma unroll
    for(int off=1; off<64; off<<=1) mx = fmaxf(mx, __shfl_xor(mx, off));
    if(l64==0) mS[s] = mx;
  }
  __syncthreads();
  #pragma unroll
  for(int s=0;s<8;s++) plT[t][s] = __expf(lg[s] - mS[s]);
  __syncthreads();
  {  // per-s chunk sum
    int s = t>>6, l64 = t&63;
    float sm = 0.f;
    #pragma unroll
    for(int k=0;k<8;k++) sm += plT[l64 + 64*k][s];
    #pragma unroll
    for(int off=1; off<64; off<<=1) sm += __shfl_xor(sm, off);
    if(l64==0) lS[s] = sm;
  }
  // acc: waves 0-3, wave w handles n = w+4j (deterministic 4-wave reduce)
  if(w < 4){
    float4 acc4[8] = {};
    const u16* base = xn + ((size_t)(b*NN) + (size_t)c*CHK)*DD;
    #pragma unroll 4
    for(int j=0;j<128;++j){
      int nl = w + 4*j;
      uint2 u = *(const uint2*)(base + (size_t)nl*DD + l*4);
      float x0=bflo(u.x), x1=bfhi(u.x), x2=bflo(u.y), x3=bfhi(u.y);
      const float4* pr = (const float4*)(&plT[nl][0]);
      float4 pa = pr[0], pb4 = pr[1];
      acc4[0].x += pa.x*x0; acc4[0].y += pa.x*x1; acc4[0].z += pa.x*x2; acc4[0].w += pa.x*x3;
      acc4[1].x += pa.y*x0; acc4[1].y += pa.y*x1; acc4[1].z += pa.y*x2; acc4[1].w += pa.y*x3;
      acc4[2].x += pa.z*x0; acc4[2].y += pa.z*x1; acc4[2].z += pa.z*x2; acc4[2].w += pa.z*x3;
      acc4[3].x += pa.w*x0; acc4[3].y += pa.w*x1; acc4[3].z += pa.w*x2; acc4[3].w += pa.w*x3;
      acc4[4].x += pb4.x*x0; acc4[4].y += pb4.x*x1; acc4[4].z += pb4.x*x2; acc4[4].w += pb4.x*x3;
      acc4[5].x += pb4.y*x0; acc4[5].y += pb4.y*x1; acc4[5].z += pb4.y*x2; acc4[5].w += pb4.y*x3;
      acc4[6].x += pb4.z*x0; acc4[6].y += pb4.z*x1; acc4[6].z += pb4.z*x2; acc4[6].w += pb4.z*x3;
      acc4[7].x += pb4.w*x0; acc4[7].y += pb4.w*x1; acc4[7].z += pb4.w*x2; acc4[7].w += pb4.w*x3;
    }
    #pragma unroll
    for(int s=0;s<8;s++) red[w][s][l] = acc4[s];
  }
  __syncthreads();
  size_t pb = (size_t)(b*NCH + c)*8;
  if(t < 512){
    int s = t>>6, ll = t&63;
    float4 r0=red[0][s][ll], r1=red[1][s][ll], r2=red[2][s][ll], r3=red[3][s][ll];
    float4 o;
    o.x=r0.x+r1.x+r2.x+r3.x; o.y=r0.y+r1.y+r2.y+r3.y;
    o.z=r0.z+r1.z+r2.z+r3.z; o.w=r0.w+r1.w+r2.w+r3.w;
    *(float4*)(aP + pb*256 + s*256 + ll*4) = o;
  }
  if(t<8){ mP[pb+t] = mS[t]; lP[pb+t] = lS[t]; }
}

// ---- combine 4 chunk partials -> U ----
__global__ __launch_bounds__(256) void k_comb(const float* __restrict__ mP, const float* __restrict__ lP,
                                              const float* __restrict__ aP, float* __restrict__ U){
  int r = blockIdx.x;            // r = b*8 + s
  int b = r>>3, s = r&7, t = threadIdx.x;
  float M = -1e30f;
  #pragma unroll
  for(int c=0;c<NCH;c++) M = fmaxf(M, mP[(b*NCH+c)*8 + s]);
  float w[NCH]; float L = 0.f;
  #pragma unroll
  for(int c=0;c<NCH;c++){ w[c] = __expf(mP[(b*NCH+c)*8+s] - M); L += lP[(b*NCH+c)*8+s]*w[c]; }
  float u = 0.f;
  #pragma unroll
  for(int c=0;c<NCH;c++) u += w[c]*aP[(size_t)((b*NCH+c)*8+s)*256 + t];
  U[r*256+t] = u / L;
}

// ---- generic tile GEMM: C = act(A[M,256] @ W[NC,256]^T + bias) ----
template<int TM, int TN, int NC, int MODE>
__device__ __forceinline__ void gemm_tile(const float* __restrict__ A, const float* __restrict__ W,
                                          const float* __restrict__ bias, const float* __restrict__ R,
                                          float* __restrict__ C, int bx, int by){
  const int tx = threadIdx.x & 15, ty = threadIdx.x >> 4;
  constexpr int MI = TM/16, NJ = TN/16;
  const int r0 = bx*TM + ty*MI, c0 = by*TN + tx*NJ;
  const float* a0 = A + (size_t)r0*256;
  const float* w0 = W + (size_t)c0*256;
  float acc[MI][NJ] = {};
  #pragma unroll 2
  for(int k=0;k<256;k+=4){
    float4 av[MI], wv[NJ];
    #pragma unroll
    for(int i=0;i<MI;i++) av[i] = *(const float4*)(a0 + i*256 + k);
    #pragma unroll
    for(int j=0;j<NJ;j++) wv[j] = *(const float4*)(w0 + j*256 + k);
    #pragma unroll
    for(int i=0;i<MI;i++)
      #pragma unroll
      for(int j=0;j<NJ;j++)
        acc[i][j] += av[i].x*wv[j].x + av[i].y*wv[j].y + av[i].z*wv[j].z + av[i].w*wv[j].w;
  }
  #pragma unroll
  for(int i=0;i<MI;i++){
    #pragma unroll
    for(int j=0;j<NJ;j++){
      float v = acc[i][j] + bias[c0+j];
      if(MODE==1) v = fmaxf(v, 0.f);
      if(MODE==2) v += R[(size_t)(r0+i)*NC + c0 + j];
      C[(size_t)(r0+i)*NC + c0 + j] = v;
    }
  }
}

__global__ __launch_bounds__(256) void k_gigh(const float* __restrict__ U, const float* __restrict__ Wihv,
                                              const float* __restrict__ bihv, const float* __restrict__ Sc,
                                              const float* __restrict__ Whh, const float* __restrict__ bhh,
                                              float* __restrict__ Gi, float* __restrict__ Gh){
  if(blockIdx.z==0) gemm_tile<64,32,768,0>(U,  Wihv, bihv, nullptr, Gi, blockIdx.x, blockIdx.y);
  else              gemm_tile<64,32,768,0>(Sc, Whh,  bhh,  nullptr, Gh, blockIdx.x, blockIdx.y);
}
__global__ __launch_bounds__(256) void k_w1(const float* __restrict__ Ln, const float* __restrict__ W1m,
                                            const float* __restrict__ b1v, float* __restrict__ H){
  gemm_tile<32,32,256,1>(Ln, W1m, b1v, nullptr, H, blockIdx.x, blockIdx.y);
}
__global__ __launch_bounds__(256) void k_w2(const float* __restrict__ H, const float* __restrict__ W2m,
                                            const float* __restrict__ b2v, const float* __restrict__ Sg,
                                            float* __restrict__ C){
  gemm_tile<32,32,256,2>(H, W2m, b2v, Sg, C, blockIdx.x, blockIdx.y);
}

// ---- GRU gates + LN_ff fused; one block per row ----
__global__ __launch_bounds__(256) void k_gates(const float* __restrict__ Gi, const float* __restrict__ Gh,
                                               const float* __restrict__ Sc, const float* __restrict__ g,
                                               const float* __restrict__ be, float* __restrict__ Sg,
                                               float* __restrict__ Ln){
  __shared__ float sh[8];
  int r = blockIdx.x, t = threadIdx.x, w = t>>6, l = t&63;
  const float* gi = Gi + (size_t)r*768;
  const float* gh = Gh + (size_t)r*768;
  float ir=gi[t], iz=gi[256+t], inn=gi[512+t];
  float hr=gh[t], hz=gh[256+t], hn=gh[512+t];
  float rr = 1.f/(1.f + __expf(-(ir+hr)));
  float zz = 1.f/(1.f + __expf(-(iz+hz)));
  float nn = tanhf(inn + rr*hn);
  float prev = Sc[r*256+t];
  float sp = (1.f-zz)*nn + zz*prev;
  Sg[r*256+t] = sp;
  float s1=sp, s2=sp*sp;
  #pragma unroll
  for(int off=1; off<64; off<<=1){ s1 += __shfl_xor(s1,off); s2 += __shfl_xor(s2,off); }
  if(l==0){ sh[w]=s1; sh[4+w]=s2; }
  __syncthreads();
  float t1=sh[0]+sh[1]+sh[2]+sh[3];
  float t2=sh[4]+sh[5]+sh[6]+sh[7];
  float m = t1*(1.f/256.f);
  float var = t2*(1.f/256.f) - m*m;
  float rs = rsqrtf(var + 1e-5f);
  Ln[r*256+t] = (sp-m)*rs*g[t] + be[t];
}

extern "C" void kernel_launch(void* const* d_in, const int* in_sizes, int n_in,
                              void* d_out, int out_size, void* d_ws, size_t ws_size,
                              hipStream_t stream){
  const float* x    = (const float*)d_in[0];
  const float* noise= (const float*)d_in[1];
  const float* mu   = (const float*)d_in[2];
  const float* sig  = (const float*)d_in[3];
  const float* Wq   = (const float*)d_in[4];
  const float* bq   = (const float*)d_in[5];
  const float* Wk   = (const float*)d_in[6];
  // d_in[7] = bk : constant shift over n, cancels in softmax
  const float* Wv   = (const float*)d_in[8];
  const float* bv   = (const float*)d_in[9];
  const float* W_ih = (const float*)d_in[10];
  const float* b_ih = (const float*)d_in[11];
  const float* W_hh = (const float*)d_in[12];
  const float* b_hh = (const float*)d_in[13];
  const float* W1m  = (const float*)d_in[14];
  const float* b1v  = (const float*)d_in[15];
  const float* W2m  = (const float*)d_in[16];
  const float* b2v  = (const float*)d_in[17];
  const float* g_in = (const float*)d_in[18];
  const float* be_in= (const float*)d_in[19];
  const float* g_sl = (const float*)d_in[20];
  const float* be_sl= (const float*)d_in[21];
  const float* g_ff = (const float*)d_in[22];
  const float* be_ff= (const float*)d_in[23];

  char* p = (char*)d_ws;
  auto alloc = [&](size_t bytes)->char*{ char* q = p; p += (bytes + 255) & ~(size_t)255; return q; };
  u16*   xn   = (u16*)  alloc((size_t)BB*NN*DD*2);
  float* Wqk  = (float*)alloc(256*256*4);
  float* bqk  = (float*)alloc(256*4);
  float* Wihv = (float*)alloc(768*256*4);
  float* bihv = (float*)alloc(768*4);
  float* Scur = (float*)alloc(512*256*4);
  float* Sg   = (float*)alloc(512*256*4);
  float* Ln   = (float*)alloc(512*256*4);
  float* Hh   = (float*)alloc(512*256*4);
  float* Uu   = (float*)alloc(512*256*4);
  float* Qq   = (float*)alloc(512*256*4);
  float* Gi   = (float*)alloc((size_t)512*768*4);
  float* Gh   = (float*)alloc((size_t)512*768*4);
  float* mP   = (float*)alloc(64*NCH*8*4);
  float* lP   = (float*)alloc(64*NCH*8*4);
  float* aP   = (float*)alloc((size_t)64*NCH*8*256*4);
  if((size_t)(p - (char*)d_ws) > ws_size) return;  // ws too small -> fail loudly

  k_init<<<1538, 256, 0, stream>>>(noise, mu, sig, Scur, Wq, Wk, bq, W_ih, Wv, bv, b_ih,
                                   Wqk, bqk, Wihv, bihv);
  k_ln<<<32768, 256, 0, stream>>>(x, g_in, be_in, xn);

  for(int it=0; it<NITER; ++it){
    k_q<<<dim3(64,4), 512, 0, stream>>>(Scur, g_sl, be_sl, Wqk, bqk, Qq);
    k_attn<<<dim3(64, NCH), 512, 0, stream>>>(xn, Qq, mP, lP, aP);
    k_comb<<<512, 256, 0, stream>>>(mP, lP, aP, Uu);
    k_gigh<<<dim3(8,24,2), 256, 0, stream>>>(Uu, Wihv, bihv, Scur, W_hh, b_hh, Gi, Gh);
    k_gates<<<512, 256, 0, stream>>>(Gi, Gh, Scur, g_ff, be_ff, Sg, Ln);
    k_w1<<<dim3(16,8), 256, 0, stream>>>(Ln, W1m, b1v, Hh);
    float* outp = (it==NITER-1) ? (float*)d_out : Scur;
    k_w2<<<dim3(16,8), 256, 0, stream>>>(Hh, W2m, b2v, Sg, outp);
  }
}